// Round 10
// baseline (119.003 us; speedup 1.0000x reference)
//
#include <hip/hip_runtime.h>
#include <hip/hip_bf16.h>

#define ETA_C  0.1f
#define BETA_C 0.05f
#define MU_C   0.05f
#define MINI_C 1e-6f

typedef __attribute__((ext_vector_type(8))) short short8;
typedef __attribute__((ext_vector_type(4))) float f32x4;

// ---------- DPP wave-64 sum ----------
template<int CTRL, int ROWMASK>
__device__ __forceinline__ float dpp_add(float x) {
  int v = __builtin_amdgcn_update_dpp(0, __float_as_int(x), CTRL, ROWMASK, 0xf, true);
  return x + __int_as_float(v);
}

__device__ __forceinline__ float wave_sum(float x) {
  x = dpp_add<0xB1,  0xF>(x);
  x = dpp_add<0x4E,  0xF>(x);
  x = dpp_add<0x141, 0xF>(x);
  x = dpp_add<0x140, 0xF>(x);
  x = dpp_add<0x142, 0xA>(x);
  x = dpp_add<0x143, 0xC>(x);
  return __int_as_float(__builtin_amdgcn_readlane(__float_as_int(x), 63));
}

__device__ __forceinline__ float rl(float x, int k) {
  return __int_as_float(__builtin_amdgcn_readlane(__float_as_int(x), k));
}

__device__ __forceinline__ short bf16r(float x) {
  unsigned u = __float_as_uint(x);
  u += 0x7fffu + ((u >> 16) & 1u);
  return (short)(u >> 16);
}

__device__ __forceinline__ float bf2f(short s) {
  return __uint_as_float(((unsigned)(unsigned short)s) << 16);
}

// ---------- kernel A: per-block column-sum partials ----------
__global__ __launch_bounds__(256) void sums_kernel(
    const float* __restrict__ seeds, const float* __restrict__ es,
    const float* __restrict__ en, float* __restrict__ part,
    float* __restrict__ out, int V, int rows_per_block, int gsr_off,
    int zeroOut) {
  __shared__ float sh[192];
  int t = threadIdx.x, bx = blockIdx.x;
  if (zeroOut) {
    if (bx < 16) out[(bx << 8) + t] = 0.f;
    else if (bx == 16 && t < 65) out[gsr_off + t] = 0.f;
  }
  if (t < 192) sh[t] = 0.f;
  __syncthreads();
  int k = t & 63, w = t >> 6;
  int v0 = bx * rows_per_block;
  int v1 = min(v0 + rows_per_block, V);
  float s0 = 0.f, s1 = 0.f, s2 = 0.f;
  for (int v = v0 + w; v < v1; v += 4) {
    int idx = (v << 6) + k;
    s0 += seeds[idx]; s1 += es[idx]; s2 += en[idx];
  }
  atomicAdd(&sh[k], s0);
  atomicAdd(&sh[64 + k], s1);
  atomicAdd(&sh[128 + k], s2);
  __syncthreads();
  if (t < 192) part[bx * 192 + t] = sh[t];
}

// ---------- kernel B: persistent-block main — preamble hoisted, tile loop ----
__global__ __launch_bounds__(1024, 4) void main_kernel(
    const float* __restrict__ bow,   // (B=64, V)
    const float* __restrict__ seeds, // (V, 64)
    const float* __restrict__ exp_m, // (64, 64)
    const float* __restrict__ exp_s, // (V, 64)
    const float* __restrict__ exp_n, // (V, 64)
    const float* __restrict__ pi,    // (64)
    const float* __restrict__ part,  // 64 x 192 column-sum partials
    float* __restrict__ out,
    float* __restrict__ wsm, float* __restrict__ wsgq,
    int V, int useWs, int gsr_off, int NB) {
  __shared__ short THbf[4096];     // bf16 th  [b][k]                  8 KB
  __shared__ short THTbf[4096];    // bf16 th^T [k][b]                 8 KB
  __shared__ short TLbf[4096];     // bf16 th*lnth [b][k]              8 KB
  __shared__ short ARRT[1024];     // bf16 arr^T [v][k]                2 KB
  __shared__ short ASVT[1024];     // bf16 (ass+asr)^T [v][k]          2 KB
  __shared__ short ARLT[1024];     // bf16 arr*ln(arr)^T [v][k]        2 KB
  __shared__ short WSRT[2048];     // bf16 [k_out][ws(16v)|wr(16v)]    4 KB
  __shared__ short PKA[2048];      // bf16 [b][cis(16v)|cir(16v)]      4 KB
  __shared__ short CIRT[1024];     // bf16 cirr^T [v][b]               2 KB
  __shared__ float RSL[64 * 17];   // r_sum [b][v]  (alias NNL)      4.25 KB
  __shared__ float SSL[64 * 17];   // s_sum [b][v]  (alias red_gsr)  4.25 KB
  __shared__ float L0a[64 * 17];   // th*arrl part  (alias redq)     4.25 KB
  __shared__ float L0b[64 * 17];   // tl*arr  part                   4.25 KB
  __shared__ float sums_sh[192];
  float* NNL = RSL;
  float* red_gsr = SSL;
  float* redq = L0a;

  int t = threadIdx.x;
  // ---- preamble: ONCE per persistent block ----
#pragma unroll
  for (int i = 0; i < 4; i++) {
    int idx = t + (i << 10);
    int b = idx >> 6, k = idx & 63;
    float th = exp_m[idx] + ETA_C;
    float lth = __logf(th);
    THbf[idx] = bf16r(th);
    THTbf[(k << 6) + b] = bf16r(th);
    TLbf[idx] = bf16r(th * lth);
  }
  if (t < 192) {
    float s = 0.f;
#pragma unroll 8
    for (int j = 0; j < 64; j++) s += part[j * 192 + t];
    sums_sh[t] = s;
  }
  __syncthreads();

  int lane = t & 63, w = t >> 6;
  int q = lane >> 4, c = lane & 15;
  float acc_g_tot = 0.f, acc_q_tot = 0.f;

  for (int tile = blockIdx.x; tile < NB; tile += gridDim.x) {
    int v = (tile << 4) + w;
    bool active = (v < V);

    // ---- phase A: per-v coefficient vectors (lane = k) ----
    float pik = 0.f, omp = 0.f, a_ss = 0.f, a_sr = 0.f, a_rr = 0.f;
    float bowpre = 0.f;
    bool seedRow = false;
    if (active) {
      int rbase = (v << 6) + lane;
      float seed = seeds[rbase];
      float es = exp_s[rbase];
      float en = exp_n[rbase];
      pik = pi[lane];
      float inv_ds = __builtin_amdgcn_rcpf(MU_C * sums_sh[lane] + sums_sh[64 + lane]);
      float inv_dn = __builtin_amdgcn_rcpf(BETA_C * (float)V + sums_sh[128 + lane]);
      float phi_s = (MU_C + es) * inv_ds;
      float phi_n = (BETA_C + en) * inv_dn;
      omp = 1.0f - pik;
      a_ss = seed * phi_s * pik;
      a_sr = seed * phi_n * omp;
      a_rr = (1.0f - seed) * phi_n;
      seedRow = (__ballot(seed > 0.f) != 0ull);
      float wsv = fmaf(pik, a_ss, omp * a_sr);
      float wrv = seedRow ? omp * a_rr : a_rr;
      float arrl = (a_rr > 0.f) ? a_rr * __logf(a_rr) : 0.f;
      ARRT[(w << 6) + lane] = bf16r(a_rr);
      ASVT[(w << 6) + lane] = bf16r(a_ss + a_sr);
      ARLT[(w << 6) + lane] = bf16r(arrl);
      WSRT[(lane << 5) + w] = bf16r(wsv);
      WSRT[(lane << 5) + 16 + w] = bf16r(wrv);
      bowpre = bow[lane * V + v];        // lane = b
    } else {
      ARRT[(w << 6) + lane] = 0;
      ASVT[(w << 6) + lane] = 0;
      ARLT[(w << 6) + lane] = 0;
      WSRT[(lane << 5) + w] = 0;
      WSRT[(lane << 5) + 16 + w] = 0;
    }
    __syncthreads();

    // ---- phase B: RS / SS / L0a / L0b MFMA matmuls ----
    {
      int job = w >> 2, mt = w & 3;
      const short* Amat = (job == 3) ? TLbf : THbf;
      const short* Bmat = (job == 0) ? ARRT : (job == 1) ? ASVT
                         : (job == 2) ? ARLT : ARRT;
      float* Cd = (job == 0) ? RSL : (job == 1) ? SSL : (job == 2) ? L0a : L0b;
      f32x4 acc = {0.f, 0.f, 0.f, 0.f};
      int arow = (mt << 4) + c;
#pragma unroll
      for (int s = 0; s < 2; s++) {
        short8 af = *(const short8*)&Amat[(arow << 6) + (s << 5) + (q << 3)];
        short8 bf = *(const short8*)&Bmat[(c << 6) + (s << 5) + (q << 3)];
        acc = __builtin_amdgcn_mfma_f32_16x16x32_bf16(af, bf, acc, 0, 0, 0);
      }
#pragma unroll
      for (int r = 0; r < 4; r++)
        Cd[((mt << 4) + (q << 2) + r) * 17 + c] = acc[r];
    }
    __syncthreads();

    // ---- phase C: per-v normalization (lane = b) + seed exact path ----
    float acc_s = 0.f, acc_g = 0.f, acc_qk = 0.f, acc_qb = 0.f;
    if (active) {
      float rsv = RSL[lane * 17 + w];
      float ssv = SSL[lane * 17 + w];
      float ivx = __builtin_amdgcn_rcpf(ssv + MINI_C);
      float ivy = __builtin_amdgcn_rcpf(rsv + MINI_C);
      float cis = bowpre * ivx;
      float cirr = bowpre * ivy;
      PKA[(lane << 5) + w] = bf16r(cis);
      PKA[(lane << 5) + 16 + w] = bf16r(cirr);
      CIRT[(w << 6) + lane] = bf16r(cirr);
      if (!seedRow) {
        float Lb = L0a[lane * 17 + w] + L0b[lane * 17 + w];
        float q0 = (bowpre > 0.f) ? ivy : 0.f;
        float q1 = q0 * __logf(ivy);
        acc_qb = fmaf(q0, Lb, q1 * rsv);
        out[4096 + V * 64 + (v << 6) + lane] = 0.f;   // temp_exp_s
      } else {
        float acc_n = 0.f;
        unsigned long long m = __ballot(bowpre > 0.f);
        while (m) {
          int b = __builtin_amdgcn_readfirstlane(__builtin_ctzll(m));
          m &= (m - 1);
          float cb = rl(bowpre, b);
          float is = rl(ivx, b), ir = rl(ivy, b);
          float th = bf2f(THbf[(b << 6) + lane]);
          float gss = th * a_ss * is;
          float gsr = th * a_sr * is;
          float grr = th * a_rr * ir;
          float gnr = gsr + grr;
          float gamma = fmaf(pik, gss, omp * gnr);
          acc_n = fmaf(gnr, cb, acc_n);
          acc_s = fmaf(gss, cb, acc_s);
          acc_g += gsr;
          acc_qk = fmaf(gamma, __logf(gamma + MINI_C), acc_qk);
        }
        out[4096 + (v << 6) + lane] = acc_n;
        out[4096 + V * 64 + (v << 6) + lane] = acc_s;
      }
    } else {
      PKA[(lane << 5) + w] = 0;
      PKA[(lane << 5) + 16 + w] = 0;
      CIRT[(w << 6) + lane] = 0;
    }
    acc_g_tot += acc_g;
    acc_q_tot += acc_qk + acc_qb;
    __syncthreads();

    // ---- phase D: P matmul (temp_exp_m partial) + N matmul (waves 12-15) ----
    {
      int tm = w >> 2, tn = w & 3;
      f32x4 acc = {0.f, 0.f, 0.f, 0.f};
      short8 af = *(const short8*)&PKA[(((tm << 4) + c) << 5) + (q << 3)];
      short8 bf = *(const short8*)&WSRT[(((tn << 4) + c) << 5) + (q << 3)];
      acc = __builtin_amdgcn_mfma_f32_16x16x32_bf16(af, bf, acc, 0, 0, 0);
#pragma unroll
      for (int r = 0; r < 4; r++) {
        int brow = (tm << 4) + (q << 2) + r;
        int kcol = (tn << 4) + c;
        float val = acc[r] * bf2f(THbf[(brow << 6) + kcol]);
        if (useWs) wsm[(size_t)tile * 4096 + (brow << 6) + kcol] = val;
        else atomicAdd(&out[(brow << 6) + kcol], val);
      }
      if (w >= 12) {
        int mt = w - 12;
        f32x4 an = {0.f, 0.f, 0.f, 0.f};
#pragma unroll
        for (int s = 0; s < 2; s++) {
          short8 a2 = *(const short8*)&THTbf[(((mt << 4) + c) << 6) + (s << 5) + (q << 3)];
          short8 b2 = *(const short8*)&CIRT[(c << 6) + (s << 5) + (q << 3)];
          an = __builtin_amdgcn_mfma_f32_16x16x32_bf16(a2, b2, an, 0, 0, 0);
        }
#pragma unroll
        for (int r = 0; r < 4; r++)
          NNL[((mt << 4) + (q << 2) + r) * 17 + c] = an[r];
      }
    }
    __syncthreads();

    // ---- phase E: temp_exp_n for non-seed rows (lane = k) ----
    if (active && !seedRow)
      out[4096 + (v << 6) + lane] = a_rr * NNL[lane * 17 + w];
    // no barrier needed before next phase A (no LDS aliasing across E->A;
    // E->B(RSL) and A->D(WSRT) hazards are covered by the A->B barrier)
  }

  __syncthreads();   // all tiles done; SSL/L0a free for epilogue aliases
  red_gsr[t] = acc_g_tot;
  float qzw = wave_sum(acc_q_tot);
  if (lane == 0) redq[w] = qzw;
  __syncthreads();

  if (w == 0) {
    float g = 0.f;
#pragma unroll
    for (int j = 0; j < 16; j++) g += red_gsr[(j << 6) + lane];
    if (useWs) wsgq[blockIdx.x * 66 + lane] = g;
    else if (g != 0.f) atomicAdd(&out[gsr_off + lane], g);
    if (t == 0) {
      float qs = 0.f;
#pragma unroll
      for (int j = 0; j < 16; j++) qs += redq[j];
      if (useWs) wsgq[blockIdx.x * 66 + 64] = qs;
      else atomicAdd(&out[gsr_off + 64], qs);
    }
  }
}

// ---------- kernel C: parallel reduce of per-block partials ----------
__global__ __launch_bounds__(1024) void reduce_kernel(
    const float* __restrict__ wsm, const float* __restrict__ wsgq,
    float* __restrict__ out, int NB, int NP, int gsr_off) {
  __shared__ float sh[1024];
  int t = threadIdx.x, lane = t & 63, w = t >> 6, bx = blockIdx.x;
  if (bx < 64) {
    int e = (bx << 6) + lane;
    float s0 = 0.f, s1 = 0.f, s2 = 0.f, s3 = 0.f;
    int j = w;
    for (; j + 48 < NB; j += 64) {
      s0 += wsm[(size_t)(j)      * 4096 + e];
      s1 += wsm[(size_t)(j + 16) * 4096 + e];
      s2 += wsm[(size_t)(j + 32) * 4096 + e];
      s3 += wsm[(size_t)(j + 48) * 4096 + e];
    }
    for (; j < NB; j += 16) s0 += wsm[(size_t)j * 4096 + e];
    sh[t] = (s0 + s1) + (s2 + s3);
    __syncthreads();
    if (w == 0) {
      float tot = 0.f;
#pragma unroll
      for (int i = 0; i < 16; i++) tot += sh[(i << 6) + lane];
      out[e] = tot;
    }
  } else if (bx == 64) {
    float s = 0.f;
    for (int j = w; j < NP; j += 16) s += wsgq[j * 66 + lane];
    sh[t] = s;
    __syncthreads();
    if (w == 0) {
      float tot = 0.f;
#pragma unroll
      for (int i = 0; i < 16; i++) tot += sh[(i << 6) + lane];
      out[gsr_off + lane] = tot;
    }
  } else {
    float s = 0.f;
    for (int j = t; j < NP; j += 1024) s += wsgq[j * 66 + 64];
    s = wave_sum(s);
    if (lane == 0) sh[w] = s;
    __syncthreads();
    if (t == 0) {
      float tot = 0.f;
#pragma unroll
      for (int i = 0; i < 16; i++) tot += sh[i];
      out[gsr_off + 64] = tot;
    }
  }
}

extern "C" void kernel_launch(void* const* d_in, const int* in_sizes, int n_in,
                              void* d_out, int out_size, void* d_ws,
                              size_t ws_size, hipStream_t stream) {
  (void)n_in; (void)out_size;
  const float* bow   = (const float*)d_in[0];
  const float* seeds = (const float*)d_in[1];
  const float* exp_m = (const float*)d_in[2];
  const float* exp_s = (const float*)d_in[3];
  const float* exp_n = (const float*)d_in[4];
  const float* pi    = (const float*)d_in[5];
  int K = in_sizes[5];          // 64
  int V = in_sizes[1] / K;      // 10000
  float* out = (float*)d_out;
  float* ws = (float*)d_ws;

  int NB = (V + 15) / 16;       // 625 tiles of 16 v
  int NP = NB < 512 ? NB : 512; // persistent blocks: 2/CU co-resident
  int gsr_off = 4096 + 2 * V * 64;

  size_t needF = (size_t)NB * 4096 + (size_t)NB * 66 + 64 * 192;
  int useWs = (ws_size >= needF * 4) ? 1 : 0;

  float* wsm  = ws;                          // NB x 4096
  float* wsgq = wsm + (size_t)NB * 4096;     // NP x 66 (gsr 64 + qz)
  float* part = wsgq + (size_t)NB * 66;      // 64 x 192

  int rpb = (V + 63) / 64;
  sums_kernel<<<64, 256, 0, stream>>>(seeds, exp_s, exp_n, part, out, V, rpb,
                                      gsr_off, useWs ? 0 : 1);
  main_kernel<<<NP, 1024, 0, stream>>>(bow, seeds, exp_m, exp_s, exp_n, pi,
                                       part, out, wsm, wsgq, V, useWs, gsr_off,
                                       NB);
  if (useWs) {
    reduce_kernel<<<66, 1024, 0, stream>>>(wsm, wsgq, out, NB, NP, gsr_off);
  }
}

// Round 11
// 111.612 us; speedup vs baseline: 1.0662x; 1.0662x over previous
//
#include <hip/hip_runtime.h>
#include <hip/hip_bf16.h>

#define ETA_C  0.1f
#define BETA_C 0.05f
#define MU_C   0.05f
#define MINI_C 1e-6f

typedef __attribute__((ext_vector_type(8))) short short8;
typedef __attribute__((ext_vector_type(4))) float f32x4;

// ---------- DPP wave-64 sum ----------
template<int CTRL, int ROWMASK>
__device__ __forceinline__ float dpp_add(float x) {
  int v = __builtin_amdgcn_update_dpp(0, __float_as_int(x), CTRL, ROWMASK, 0xf, true);
  return x + __int_as_float(v);
}

__device__ __forceinline__ float wave_sum(float x) {
  x = dpp_add<0xB1,  0xF>(x);
  x = dpp_add<0x4E,  0xF>(x);
  x = dpp_add<0x141, 0xF>(x);
  x = dpp_add<0x140, 0xF>(x);
  x = dpp_add<0x142, 0xA>(x);
  x = dpp_add<0x143, 0xC>(x);
  return __int_as_float(__builtin_amdgcn_readlane(__float_as_int(x), 63));
}

__device__ __forceinline__ float rl(float x, int k) {
  return __int_as_float(__builtin_amdgcn_readlane(__float_as_int(x), k));
}

__device__ __forceinline__ short bf16r(float x) {
  unsigned u = __float_as_uint(x);
  u += 0x7fffu + ((u >> 16) & 1u);
  return (short)(u >> 16);
}

__device__ __forceinline__ float bf2f(short s) {
  return __uint_as_float(((unsigned)(unsigned short)s) << 16);
}

// ---------- kernel A: per-block column-sum partials + zero atomic dests ----
__global__ __launch_bounds__(256) void sums_kernel(
    const float* __restrict__ seeds, const float* __restrict__ es,
    const float* __restrict__ en, float* __restrict__ part,
    float* __restrict__ out, int V, int rows_per_block, int gsr_off) {
  __shared__ float sh[192];
  int t = threadIdx.x, bx = blockIdx.x;
  if (bx < 16) out[(bx << 8) + t] = 0.f;               // temp_exp_m accum
  else if (bx == 16 && t < 65) out[gsr_off + t] = 0.f; // gsr + qz
  if (t < 192) sh[t] = 0.f;
  __syncthreads();
  int k = t & 63, w = t >> 6;
  int v0 = bx * rows_per_block;
  int v1 = min(v0 + rows_per_block, V);
  float s0 = 0.f, s1 = 0.f, s2 = 0.f;
  for (int v = v0 + w; v < v1; v += 4) {
    int idx = (v << 6) + k;
    s0 += seeds[idx]; s1 += es[idx]; s2 += en[idx];
  }
  atomicAdd(&sh[k], s0);
  atomicAdd(&sh[64 + k], s1);
  atomicAdd(&sh[128 + k], s2);
  __syncthreads();
  if (t < 192) part[bx * 192 + t] = sh[t];
}

// ---------- kernel B: persistent main — MFMA K-accumulation across tiles ----
__global__ __launch_bounds__(1024, 4) void main_kernel(
    const float* __restrict__ bow,   // (B=64, V)
    const float* __restrict__ seeds, // (V, 64)
    const float* __restrict__ exp_m, // (64, 64)
    const float* __restrict__ exp_s, // (V, 64)
    const float* __restrict__ exp_n, // (V, 64)
    const float* __restrict__ pi,    // (64)
    const float* __restrict__ part,  // 64 x 192 column-sum partials
    float* __restrict__ out,
    int V, int gsr_off, int NB) {
  __shared__ short THbf[4096];     // bf16 th  [b][k]                  8 KB
  __shared__ short THTbf[4096];    // bf16 th^T [k][b]                 8 KB
  __shared__ short TLbf[4096];     // bf16 th*lnth [b][k]              8 KB
  __shared__ short ARRT[1024];     // bf16 arr^T [v][k]                2 KB
  __shared__ short ASVT[1024];     // bf16 (ass+asr)^T [v][k]          2 KB
  __shared__ short ARLT[1024];     // bf16 arr*ln(arr)^T [v][k]        2 KB
  __shared__ short WSRT[2048];     // bf16 [k_out][ws(16v)|wr(16v)]    4 KB
  __shared__ short PKA[2048];      // bf16 [b][cis(16v)|cir(16v)]      4 KB
  __shared__ short CIRT[1024];     // bf16 cirr^T [v][b]               2 KB
  __shared__ float RSL[64 * 17];   // r_sum [b][v]  (alias NNL)      4.25 KB
  __shared__ float SSL[64 * 17];   // s_sum [b][v]  (alias red_gsr)  4.25 KB
  __shared__ float L0a[64 * 17];   // th*arrl part  (alias redq)     4.25 KB
  __shared__ float L0b[64 * 17];   // tl*arr  part                   4.25 KB
  __shared__ float sums_sh[192];
  float* NNL = RSL;
  float* red_gsr = SSL;
  float* redq = L0a;

  int t = threadIdx.x;
  // ---- preamble: once per persistent block ----
#pragma unroll
  for (int i = 0; i < 4; i++) {
    int idx = t + (i << 10);
    int b = idx >> 6, k = idx & 63;
    float th = exp_m[idx] + ETA_C;
    float lth = __logf(th);
    THbf[idx] = bf16r(th);
    THTbf[(k << 6) + b] = bf16r(th);
    TLbf[idx] = bf16r(th * lth);
  }
  if (t < 192) {
    float s = 0.f;
#pragma unroll 8
    for (int j = 0; j < 64; j++) s += part[j * 192 + t];
    sums_sh[t] = s;
  }
  __syncthreads();

  int lane = t & 63, w = t >> 6;
  int q = lane >> 4, c = lane & 15;
  float acc_g_tot = 0.f, acc_q_tot = 0.f;
  f32x4 accP = {0.f, 0.f, 0.f, 0.f};   // temp_exp_m tile, carried across tiles

  for (int tile = blockIdx.x; tile < NB; tile += gridDim.x) {
    int v = (tile << 4) + w;
    bool active = (v < V);

    // ---- phase A: per-v coefficient vectors (lane = k) ----
    float pik = 0.f, omp = 0.f, a_ss = 0.f, a_sr = 0.f, a_rr = 0.f;
    float bowpre = 0.f;
    bool seedRow = false;
    if (active) {
      int rbase = (v << 6) + lane;
      float seed = seeds[rbase];
      float es = exp_s[rbase];
      float en = exp_n[rbase];
      pik = pi[lane];
      float inv_ds = __builtin_amdgcn_rcpf(MU_C * sums_sh[lane] + sums_sh[64 + lane]);
      float inv_dn = __builtin_amdgcn_rcpf(BETA_C * (float)V + sums_sh[128 + lane]);
      float phi_s = (MU_C + es) * inv_ds;
      float phi_n = (BETA_C + en) * inv_dn;
      omp = 1.0f - pik;
      a_ss = seed * phi_s * pik;
      a_sr = seed * phi_n * omp;
      a_rr = (1.0f - seed) * phi_n;
      seedRow = (__ballot(seed > 0.f) != 0ull);
      float wsv = fmaf(pik, a_ss, omp * a_sr);
      float wrv = seedRow ? omp * a_rr : a_rr;
      float arrl = (a_rr > 0.f) ? a_rr * __logf(a_rr) : 0.f;
      ARRT[(w << 6) + lane] = bf16r(a_rr);
      ASVT[(w << 6) + lane] = bf16r(a_ss + a_sr);
      ARLT[(w << 6) + lane] = bf16r(arrl);
      WSRT[(lane << 5) + w] = bf16r(wsv);
      WSRT[(lane << 5) + 16 + w] = bf16r(wrv);
      bowpre = bow[lane * V + v];        // lane = b
    } else {
      ARRT[(w << 6) + lane] = 0;
      ASVT[(w << 6) + lane] = 0;
      ARLT[(w << 6) + lane] = 0;
      WSRT[(lane << 5) + w] = 0;
      WSRT[(lane << 5) + 16 + w] = 0;
    }
    __syncthreads();

    // ---- phase B: RS / SS / L0a / L0b MFMA matmuls ----
    {
      int job = w >> 2, mt = w & 3;
      const short* Amat = (job == 3) ? TLbf : THbf;
      const short* Bmat = (job == 0) ? ARRT : (job == 1) ? ASVT
                         : (job == 2) ? ARLT : ARRT;
      float* Cd = (job == 0) ? RSL : (job == 1) ? SSL : (job == 2) ? L0a : L0b;
      f32x4 acc = {0.f, 0.f, 0.f, 0.f};
      int arow = (mt << 4) + c;
#pragma unroll
      for (int s = 0; s < 2; s++) {
        short8 af = *(const short8*)&Amat[(arow << 6) + (s << 5) + (q << 3)];
        short8 bf = *(const short8*)&Bmat[(c << 6) + (s << 5) + (q << 3)];
        acc = __builtin_amdgcn_mfma_f32_16x16x32_bf16(af, bf, acc, 0, 0, 0);
      }
#pragma unroll
      for (int r = 0; r < 4; r++)
        Cd[((mt << 4) + (q << 2) + r) * 17 + c] = acc[r];
    }
    __syncthreads();

    // ---- phase C: per-v normalization (lane = b) + seed exact path ----
    float acc_s = 0.f, acc_g = 0.f, acc_qk = 0.f, acc_qb = 0.f;
    if (active) {
      float rsv = RSL[lane * 17 + w];
      float ssv = SSL[lane * 17 + w];
      float ivx = __builtin_amdgcn_rcpf(ssv + MINI_C);
      float ivy = __builtin_amdgcn_rcpf(rsv + MINI_C);
      float cis = bowpre * ivx;
      float cirr = bowpre * ivy;
      PKA[(lane << 5) + w] = bf16r(cis);
      PKA[(lane << 5) + 16 + w] = bf16r(cirr);
      CIRT[(w << 6) + lane] = bf16r(cirr);
      if (!seedRow) {
        float Lb = L0a[lane * 17 + w] + L0b[lane * 17 + w];
        float q0 = (bowpre > 0.f) ? ivy : 0.f;
        float q1 = q0 * __logf(ivy);
        acc_qb = fmaf(q0, Lb, q1 * rsv);
        out[4096 + V * 64 + (v << 6) + lane] = 0.f;   // temp_exp_s
      } else {
        float acc_n = 0.f;
        unsigned long long m = __ballot(bowpre > 0.f);
        while (m) {
          int b = __builtin_amdgcn_readfirstlane(__builtin_ctzll(m));
          m &= (m - 1);
          float cb = rl(bowpre, b);
          float is = rl(ivx, b), ir = rl(ivy, b);
          float th = bf2f(THbf[(b << 6) + lane]);
          float gss = th * a_ss * is;
          float gsr = th * a_sr * is;
          float grr = th * a_rr * ir;
          float gnr = gsr + grr;
          float gamma = fmaf(pik, gss, omp * gnr);
          acc_n = fmaf(gnr, cb, acc_n);
          acc_s = fmaf(gss, cb, acc_s);
          acc_g += gsr;
          acc_qk = fmaf(gamma, __logf(gamma + MINI_C), acc_qk);
        }
        out[4096 + (v << 6) + lane] = acc_n;
        out[4096 + V * 64 + (v << 6) + lane] = acc_s;
      }
    } else {
      PKA[(lane << 5) + w] = 0;
      PKA[(lane << 5) + 16 + w] = 0;
      CIRT[(w << 6) + lane] = 0;
    }
    acc_g_tot += acc_g;
    acc_q_tot += acc_qk + acc_qb;
    __syncthreads();

    // ---- phase D: P matmul K-accumulated into accP + N matmul (w 12-15) ----
    {
      int tm = w >> 2, tn = w & 3;
      short8 af = *(const short8*)&PKA[(((tm << 4) + c) << 5) + (q << 3)];
      short8 bf = *(const short8*)&WSRT[(((tn << 4) + c) << 5) + (q << 3)];
      accP = __builtin_amdgcn_mfma_f32_16x16x32_bf16(af, bf, accP, 0, 0, 0);
      if (w >= 12) {
        int mt = w - 12;
        f32x4 an = {0.f, 0.f, 0.f, 0.f};
#pragma unroll
        for (int s = 0; s < 2; s++) {
          short8 a2 = *(const short8*)&THTbf[(((mt << 4) + c) << 6) + (s << 5) + (q << 3)];
          short8 b2 = *(const short8*)&CIRT[(c << 6) + (s << 5) + (q << 3)];
          an = __builtin_amdgcn_mfma_f32_16x16x32_bf16(a2, b2, an, 0, 0, 0);
        }
#pragma unroll
        for (int r = 0; r < 4; r++)
          NNL[((mt << 4) + (q << 2) + r) * 17 + c] = an[r];
      }
    }
    __syncthreads();

    // ---- phase E: temp_exp_n for non-seed rows (lane = k) ----
    if (active && !seedRow)
      out[4096 + (v << 6) + lane] = a_rr * NNL[lane * 17 + w];
  }

  // ---- epilogue: finalize temp_exp_m / gsr / qz with device atomics ----
  {
    int tm = w >> 2, tn = w & 3;
#pragma unroll
    for (int r = 0; r < 4; r++) {
      int brow = (tm << 4) + (q << 2) + r;
      int kcol = (tn << 4) + c;
      float val = accP[r] * bf2f(THbf[(brow << 6) + kcol]);
      atomicAdd(&out[(brow << 6) + kcol], val);
    }
  }
  __syncthreads();   // tiles done; SSL/L0a free for epilogue aliases
  red_gsr[t] = acc_g_tot;
  float qzw = wave_sum(acc_q_tot);
  if (lane == 0) redq[w] = qzw;
  __syncthreads();

  if (w == 0) {
    float g = 0.f;
#pragma unroll
    for (int j = 0; j < 16; j++) g += red_gsr[(j << 6) + lane];
    if (g != 0.f) atomicAdd(&out[gsr_off + lane], g);   // 473/512 blocks skip
    if (t == 0) {
      float qs = 0.f;
#pragma unroll
      for (int j = 0; j < 16; j++) qs += redq[j];
      atomicAdd(&out[gsr_off + 64], qs);
    }
  }
}

extern "C" void kernel_launch(void* const* d_in, const int* in_sizes, int n_in,
                              void* d_out, int out_size, void* d_ws,
                              size_t ws_size, hipStream_t stream) {
  (void)n_in; (void)out_size; (void)ws_size;
  const float* bow   = (const float*)d_in[0];
  const float* seeds = (const float*)d_in[1];
  const float* exp_m = (const float*)d_in[2];
  const float* exp_s = (const float*)d_in[3];
  const float* exp_n = (const float*)d_in[4];
  const float* pi    = (const float*)d_in[5];
  int K = in_sizes[5];          // 64
  int V = in_sizes[1] / K;      // 10000
  float* out = (float*)d_out;
  float* part = (float*)d_ws;   // 64 x 192 floats = 48 KB

  int NB = (V + 15) / 16;       // 625 tiles of 16 v
  int NP = NB < 512 ? NB : 512; // persistent blocks: 2/CU co-resident
  int gsr_off = 4096 + 2 * V * 64;
  int rpb = (V + 63) / 64;

  sums_kernel<<<64, 256, 0, stream>>>(seeds, exp_s, exp_n, part, out, V, rpb,
                                      gsr_off);
  main_kernel<<<NP, 1024, 0, stream>>>(bow, seeds, exp_m, exp_s, exp_n, pi,
                                       part, out, V, gsr_off, NB);
}